// Round 1
// baseline (630.039 us; speedup 1.0000x reference)
//
#include <hip/hip_runtime.h>

typedef unsigned short u16;
typedef short bf8 __attribute__((ext_vector_type(8)));   // 8 bf16 = one MFMA A/B frag
typedef float f4 __attribute__((ext_vector_type(4)));    // one MFMA C/D frag

#define N_EDGE    1600000
#define EDGE_TILE 128
#define NBLOCKS   (N_EDGE / EDGE_TILE)   // 12500 exact

// RNE f32 -> bf16
__device__ __forceinline__ u16 f2bf(float x) {
  union { float f; unsigned u; } v; v.f = x;
  unsigned r = v.u + 0x7FFFu + ((v.u >> 16) & 1u);
  return (u16)(r >> 16);
}

// ---------------- prep: cast/transpose weights (and nodes) to bf16 in ws ----------
// w1t layout: [5 k-slices][320 hcol][40 (32 k + 8 pad)] bf16  (pad -> 80B rows, conflict-free b128)
// w2t layout: [32 outcol][320 hcol] bf16
// nodes_bf:   [50000][64] bf16
__global__ void prep_kernel(const float* __restrict__ nodes,
                            const float* __restrict__ W1,
                            const float* __restrict__ W2,
                            u16* __restrict__ w1t,
                            u16* __restrict__ w2t,
                            u16* __restrict__ nodes_bf) {
  const int b = blockIdx.x, t = threadIdx.x;
  if (b < 200) {
    const int i = b * 256 + t;           // i = k*320 + hcol, coalesced read of W1
    const int k = i / 320;
    const int hcol = i - k * 320;
    w1t[((k >> 5) * 320 + hcol) * 40 + (k & 31)] = f2bf(W1[i]);
  } else if (b < 240) {
    const int i = (b - 200) * 256 + t;   // i = hcol*32 + outcol, coalesced read of W2
    const int hcol = i >> 5;
    const int outcol = i & 31;
    w2t[outcol * 320 + hcol] = f2bf(W2[i]);
  } else {
    const int i = (b - 240) * 256 + t;   // float4 index into nodes (800000 total)
    const float4 v = ((const float4*)nodes)[i];
    ushort4 o;
    o.x = f2bf(v.x); o.y = f2bf(v.y); o.z = f2bf(v.z); o.w = f2bf(v.w);
    ((ushort4*)nodes_bf)[i] = o;
  }
}

// ---------------- fused edge MLP ----------------
// Block: 256 thr (4 waves), 128 edges.
// GEMM1 (transposed): C1^T[320 hcol x 128 edge] = W1^T x feats^T, wave w owns hcols [80w,80w+80).
// GEMM2 (transposed): out^T[32 x 128] = W2^T x h^T, wave w owns edges [32w,32w+32), K=320 in 2 passes.
__launch_bounds__(256, 2)
__global__ void edge_mlp(const float* __restrict__ edges,
                         const int*   __restrict__ senders,
                         const int*   __restrict__ receivers,
                         const float* __restrict__ nodes_f,
                         const u16*   __restrict__ nodes_bf,
                         const u16*   __restrict__ w1t,   // [5][320][40]
                         const float* __restrict__ b1,
                         const u16*   __restrict__ w2t,   // [32][320]
                         const float* __restrict__ b2,
                         float* __restrict__ out,
                         int use_bf) {
  // LDS: phase1 = w1 slice [320][40] (25600B) + feats [128][168] (43008B) = 68608B
  //      phase2 = h [128][168] (43008B), reuses the front of the same buffer
  __shared__ __align__(16) u16 smem[34304];
  u16* w1s   = smem;            // [320][40]
  u16* feats = smem + 12800;    // [128][168] rows stride 336B = 21*16B (uniform bank quads)
  u16* hbuf  = smem;            // [128][168] phase2

  const int tid  = threadIdx.x;
  const int lane = tid & 63;
  const int wid  = tid >> 6;
  const int l15  = lane & 15;
  const int g    = lane >> 4;
  const long e0  = (long)blockIdx.x * EDGE_TILE;

  // ---- stage feats tile: [128][160] bf16 = [sender64 | receiver64 | edge32] ----
  {
    const int e  = tid >> 1;          // 2 threads per edge row
    const int h2 = tid & 1;           // half: chunks 0-9 / 10-19 (16B chunks)
    const long ge = e0 + e;
    const int si = senders[ge];
    const int ri = receivers[ge];
    u16* dst = feats + e * 168;
    #pragma unroll
    for (int i = 0; i < 10; ++i) {
      const int c = h2 * 10 + i;      // compile-time after unroll
      if (c < 16) {
        const int node = (c < 8) ? si : ri;
        const int cc = c & 7;
        if (use_bf) {
          *(int4*)(dst + c * 8) = *(const int4*)(nodes_bf + (long)node * 64 + cc * 8);
        } else {
          const float* src = nodes_f + (long)node * 64 + cc * 8;
          const float4 v0 = *(const float4*)src;
          const float4 v1 = *(const float4*)(src + 4);
          ushort4 a, b;
          a.x = f2bf(v0.x); a.y = f2bf(v0.y); a.z = f2bf(v0.z); a.w = f2bf(v0.w);
          b.x = f2bf(v1.x); b.y = f2bf(v1.y); b.z = f2bf(v1.z); b.w = f2bf(v1.w);
          *(ushort4*)(dst + c * 8)     = a;
          *(ushort4*)(dst + c * 8 + 4) = b;
        }
      } else {
        const float* src = edges + ge * 32 + (c - 16) * 8;
        const float4 v0 = *(const float4*)src;
        const float4 v1 = *(const float4*)(src + 4);
        ushort4 a, b;
        a.x = f2bf(v0.x); a.y = f2bf(v0.y); a.z = f2bf(v0.z); a.w = f2bf(v0.w);
        b.x = f2bf(v1.x); b.y = f2bf(v1.y); b.z = f2bf(v1.z); b.w = f2bf(v1.w);
        *(ushort4*)(dst + c * 8)     = a;
        *(ushort4*)(dst + c * 8 + 4) = b;
      }
    }
  }

  // ---- GEMM1: acc[af][ef] -> C1^T[hcol = 80*wid+16*af+4*g+r][edge = 16*ef+l15] ----
  f4 acc[5][8];
  #pragma unroll
  for (int af = 0; af < 5; ++af)
    #pragma unroll
    for (int ef = 0; ef < 8; ++ef)
      acc[af][ef] = (f4){0.f, 0.f, 0.f, 0.f};

  const int hbase = 80 * wid;

  for (int kk = 0; kk < 5; ++kk) {
    __syncthreads();                               // feats staged / prev compute done
    {                                              // stage W1 k-slice kk (contiguous 25600B)
      const int4* src = (const int4*)(w1t + kk * 12800);
      int4* dstv = (int4*)w1s;
      #pragma unroll
      for (int j = 0; j < 6; ++j) dstv[tid + j * 256] = src[tid + j * 256];
      if (tid < 64) dstv[tid + 1536] = src[tid + 1536];
    }
    __syncthreads();

    bf8 afr[5], bfr[8];
    #pragma unroll
    for (int af = 0; af < 5; ++af)
      afr[af] = *(const bf8*)(w1s + (hbase + 16 * af + l15) * 40 + 8 * g);
    #pragma unroll
    for (int ef = 0; ef < 8; ++ef)
      bfr[ef] = *(const bf8*)(feats + (16 * ef + l15) * 168 + kk * 32 + 8 * g);
    #pragma unroll
    for (int af = 0; af < 5; ++af)
      #pragma unroll
      for (int ef = 0; ef < 8; ++ef)
        acc[af][ef] = __builtin_amdgcn_mfma_f32_16x16x32_bf16(afr[af], bfr[ef], acc[af][ef], 0, 0, 0);
  }

  // ---- bias + sigmoid, in place ----
  #pragma unroll
  for (int af = 0; af < 5; ++af) {
    const f4 bv = *(const f4*)(b1 + hbase + 16 * af + 4 * g);   // b1[hcol], r=0..3
    #pragma unroll
    for (int ef = 0; ef < 8; ++ef) {
      #pragma unroll
      for (int r = 0; r < 4; ++r) {
        const float z  = acc[af][ef][r] + bv[r];
        const float ex = __builtin_amdgcn_exp2f(z * -1.44269504f);
        acc[af][ef][r] = __builtin_amdgcn_rcpf(1.0f + ex);
      }
    }
  }

  // ---- GEMM2 in 2 half-K passes (h half written to LDS, then consumed) ----
  f4 acc2[2][2];
  #pragma unroll
  for (int am = 0; am < 2; ++am)
    #pragma unroll
    for (int bn = 0; bn < 2; ++bn)
      acc2[am][bn] = (f4){0.f, 0.f, 0.f, 0.f};

  const int we = 32 * wid;
  #pragma unroll
  for (int p = 0; p < 2; ++p) {
    __syncthreads();                       // previous pass reads (or GEMM1) complete
    if ((wid >> 1) == p) {                 // waves whose hcols fall in this half write h
      const int hloc = 80 * (wid & 1);
      #pragma unroll
      for (int af = 0; af < 5; ++af) {
        #pragma unroll
        for (int ef = 0; ef < 8; ++ef) {
          ushort4 q;
          q.x = f2bf(acc[af][ef][0]);
          q.y = f2bf(acc[af][ef][1]);
          q.z = f2bf(acc[af][ef][2]);
          q.w = f2bf(acc[af][ef][3]);      // 4 contiguous hcols, fixed edge
          *(ushort4*)(hbuf + (16 * ef + l15) * 168 + hloc + 16 * af + 4 * g) = q;
        }
      }
    }
    __syncthreads();
    #pragma unroll
    for (int kk = 0; kk < 5; ++kk) {
      const int kb = p * 160 + kk * 32 + 8 * g;
      const bf8 a0 = *(const bf8*)(w2t + l15 * 320 + kb);          // W2^T, L1-resident
      const bf8 a1 = *(const bf8*)(w2t + (16 + l15) * 320 + kb);
      const bf8 h0 = *(const bf8*)(hbuf + (we + l15) * 168 + kk * 32 + 8 * g);
      const bf8 h1 = *(const bf8*)(hbuf + (we + 16 + l15) * 168 + kk * 32 + 8 * g);
      acc2[0][0] = __builtin_amdgcn_mfma_f32_16x16x32_bf16(a0, h0, acc2[0][0], 0, 0, 0);
      acc2[0][1] = __builtin_amdgcn_mfma_f32_16x16x32_bf16(a0, h1, acc2[0][1], 0, 0, 0);
      acc2[1][0] = __builtin_amdgcn_mfma_f32_16x16x32_bf16(a1, h0, acc2[1][0], 0, 0, 0);
      acc2[1][1] = __builtin_amdgcn_mfma_f32_16x16x32_bf16(a1, h1, acc2[1][1], 0, 0, 0);
    }
  }

  // ---- epilogue: + b2, store out[edge][32] f32 as contiguous float4s ----
  #pragma unroll
  for (int am = 0; am < 2; ++am) {
    const f4 b2v = *(const f4*)(b2 + 16 * am + 4 * g);
    #pragma unroll
    for (int bn = 0; bn < 2; ++bn) {
      const f4 v = acc2[am][bn] + b2v;
      const long e = e0 + we + 16 * bn + l15;
      *(f4*)(out + e * 32 + 16 * am + 4 * g) = v;
    }
  }
}

extern "C" void kernel_launch(void* const* d_in, const int* in_sizes, int n_in,
                              void* d_out, int out_size, void* d_ws, size_t ws_size,
                              hipStream_t stream) {
  const float* nodes     = (const float*)d_in[0];
  const float* edges     = (const float*)d_in[1];
  const int*   senders   = (const int*)d_in[2];
  const int*   receivers = (const int*)d_in[3];
  const float* W1        = (const float*)d_in[4];
  const float* b1        = (const float*)d_in[5];
  const float* W2        = (const float*)d_in[6];
  const float* b2        = (const float*)d_in[7];
  float* out             = (float*)d_out;

  u16* w1t      = (u16*)d_ws;          // 64000 elems = 128000 B
  u16* w2t      = w1t + 64000;         // 10240 elems = 20480 B
  u16* nodes_bf = w2t + 10240;         // 3.2M elems = 6.4 MB (optional)
  const int use_bf = (ws_size >= (size_t)(148480 + 6400000)) ? 1 : 0;

  const int prep_blocks = use_bf ? (240 + 3125) : 240;
  prep_kernel<<<prep_blocks, 256, 0, stream>>>(nodes, W1, W2, w1t, w2t, nodes_bf);
  edge_mlp<<<NBLOCKS, 256, 0, stream>>>(edges, senders, receivers, nodes, nodes_bf,
                                        w1t, b1, w2t, b2, out, use_bf);
}

// Round 2
// 471.128 us; speedup vs baseline: 1.3373x; 1.3373x over previous
//
#include <hip/hip_runtime.h>

typedef unsigned short u16;
typedef short bf8 __attribute__((ext_vector_type(8)));   // 8 bf16 = one MFMA A/B frag
typedef u16  u16x8 __attribute__((ext_vector_type(8)));
typedef float f4 __attribute__((ext_vector_type(4)));    // one MFMA C/D frag

#define N_EDGE    1600000
#define EDGE_TILE 64
#define NBLOCKS   (N_EDGE / EDGE_TILE)   // 25000 exact

// RNE f32 -> bf16
__device__ __forceinline__ u16 f2bf(float x) {
  union { float f; unsigned u; } v; v.f = x;
  unsigned r = v.u + 0x7FFFu + ((v.u >> 16) & 1u);
  return (u16)(r >> 16);
}

// convert 8 contiguous f32 -> 8 bf16, one 16B store
__device__ __forceinline__ void cvt8(const float* __restrict__ s, u16* __restrict__ d) {
  const float4 v0 = *(const float4*)s;
  const float4 v1 = *(const float4*)(s + 4);
  u16x8 o;
  o[0] = f2bf(v0.x); o[1] = f2bf(v0.y); o[2] = f2bf(v0.z); o[3] = f2bf(v0.w);
  o[4] = f2bf(v1.x); o[5] = f2bf(v1.y); o[6] = f2bf(v1.z); o[7] = f2bf(v1.w);
  *(u16x8*)d = o;
}

// ---------------- prep: cast/transpose weights (and nodes) to bf16 in ws ----------
// w1t layout: [5 k-slices][320 hcol][32 k] bf16 (fragment-contiguous, read from L2 per-block)
// w2t layout: [32 outcol][320 hcol] bf16
// nodes_bf:   [50000][64] bf16
__global__ void prep_kernel(const float* __restrict__ nodes,
                            const float* __restrict__ W1,
                            const float* __restrict__ W2,
                            u16* __restrict__ w1t,
                            u16* __restrict__ w2t,
                            u16* __restrict__ nodes_bf) {
  const int b = blockIdx.x, t = threadIdx.x;
  if (b < 200) {
    const int i = b * 256 + t;           // i = k*320 + hcol, coalesced read of W1
    const int k = i / 320;
    const int hcol = i - k * 320;
    w1t[((k >> 5) * 320 + hcol) * 32 + (k & 31)] = f2bf(W1[i]);
  } else if (b < 240) {
    const int i = (b - 200) * 256 + t;   // i = hcol*32 + outcol, coalesced read of W2
    const int hcol = i >> 5;
    const int outcol = i & 31;
    w2t[outcol * 320 + hcol] = f2bf(W2[i]);
  } else {
    const int i = (b - 240) * 256 + t;   // float4 index into nodes (800000 total)
    const float4 v = ((const float4*)nodes)[i];
    ushort4 o;
    o.x = f2bf(v.x); o.y = f2bf(v.y); o.z = f2bf(v.z); o.w = f2bf(v.w);
    ((ushort4*)nodes_bf)[i] = o;
  }
}

// ---------------- fused edge MLP ----------------
// Block: 256 thr (4 waves), 64 edges.
// GEMM1 (transposed): C1^T[320 hcol x 64 edge] = W1^T x feats^T; wave w owns hcols [80w,80w+80).
//   W1 fragments read directly from L2 (no LDS staging).
// GEMM2 (transposed): out^T[32 x 64] = W2^T x h^T; wave w owns edges [16w,16w+16), K=320 in 2 passes.
__launch_bounds__(256, 3)
__global__ void edge_mlp(const float* __restrict__ edges,
                         const int*   __restrict__ senders,
                         const int*   __restrict__ receivers,
                         const float* __restrict__ nodes_f,
                         const u16*   __restrict__ nodes_bf,
                         const u16*   __restrict__ w1t,   // [5][320][32]
                         const float* __restrict__ b1,
                         const u16*   __restrict__ w2t,   // [32][320]
                         const float* __restrict__ b2,
                         float* __restrict__ out,
                         int use_bf) {
  // LDS: feats [64][168] bf16 (160 cols + 8 pad -> 336B rows, 2-way bank pattern = free),
  //      then aliased as h-half [64][168] in GEMM2. 21504 B total -> LDS never binds occupancy.
  __shared__ __align__(16) u16 smem[10752];
  u16* feats = smem;
  u16* hbuf  = smem;

  const int tid  = threadIdx.x;
  const int lane = tid & 63;
  const int wid  = tid >> 6;
  const int l15  = lane & 15;
  const int g    = lane >> 4;
  const long e0  = (long)blockIdx.x * EDGE_TILE;

  // ---- stage feats tile: [64][160] bf16 = [sender64 | receiver64 | edge32], 4 thr/edge ----
  {
    const int e  = tid >> 2;
    const int h4 = tid & 3;
    const long ge = e0 + e;
    const int node = (h4 < 2) ? senders[ge] : receivers[ge];
    u16* dst = feats + e * 168;
    u16* nd  = dst + h4 * 32;             // this thread's 32-col node slice
    if (use_bf) {
      const u16* src = nodes_bf + (long)node * 64 + (h4 & 1) * 32;
      *(int4*)(nd)      = *(const int4*)(src);
      *(int4*)(nd + 8)  = *(const int4*)(src + 8);
      *(int4*)(nd + 16) = *(const int4*)(src + 16);
      *(int4*)(nd + 24) = *(const int4*)(src + 24);
    } else {
      const float* src = nodes_f + (long)node * 64 + (h4 & 1) * 32;
      cvt8(src,      nd);
      cvt8(src + 8,  nd + 8);
      cvt8(src + 16, nd + 16);
      cvt8(src + 24, nd + 24);
    }
    cvt8(edges + ge * 32 + h4 * 8, dst + 128 + h4 * 8);   // edge feat slice
  }

  const int hbase = 80 * wid;

  // b1 fragment (broadcast within 16-lane groups, L1-resident)
  f4 bv[5];
  #pragma unroll
  for (int af = 0; af < 5; ++af)
    bv[af] = *(const f4*)(b1 + hbase + 16 * af + 4 * g);

  __syncthreads();

  // ---- GEMM1: acc[af][ef] -> C1^T[hcol = hbase+16af+4g+r][edge = 16ef+l15] ----
  f4 acc[5][4];
  #pragma unroll
  for (int af = 0; af < 5; ++af)
    #pragma unroll
    for (int ef = 0; ef < 4; ++ef)
      acc[af][ef] = (f4){0.f, 0.f, 0.f, 0.f};

  const u16* wp = w1t + (hbase + l15) * 32 + 8 * g;   // per-lane W1^T base

  #pragma unroll 2
  for (int kk = 0; kk < 5; ++kk) {
    bf8 bfr[4];
    #pragma unroll
    for (int ef = 0; ef < 4; ++ef)
      bfr[ef] = *(const bf8*)(feats + (16 * ef + l15) * 168 + kk * 32 + 8 * g);
    bf8 afr[5];
    #pragma unroll
    for (int af = 0; af < 5; ++af)
      afr[af] = *(const bf8*)(wp + kk * 10240 + af * 512);   // 1KB coalesced per frag, L2-hit
    #pragma unroll
    for (int af = 0; af < 5; ++af)
      #pragma unroll
      for (int ef = 0; ef < 4; ++ef)
        acc[af][ef] = __builtin_amdgcn_mfma_f32_16x16x32_bf16(afr[af], bfr[ef], acc[af][ef], 0, 0, 0);
  }

  // ---- bias + sigmoid, in place ----
  #pragma unroll
  for (int af = 0; af < 5; ++af) {
    #pragma unroll
    for (int ef = 0; ef < 4; ++ef) {
      #pragma unroll
      for (int r = 0; r < 4; ++r) {
        const float z  = acc[af][ef][r] + bv[af][r];
        const float ex = __builtin_amdgcn_exp2f(z * -1.44269504f);
        acc[af][ef][r] = __builtin_amdgcn_rcpf(1.0f + ex);
      }
    }
  }

  // ---- GEMM2 in 2 half-K passes (h half in LDS, aliases feats) ----
  f4 acc2[2];
  acc2[0] = (f4){0.f, 0.f, 0.f, 0.f};
  acc2[1] = (f4){0.f, 0.f, 0.f, 0.f};

  const int we = 16 * wid;
  #pragma unroll
  for (int p = 0; p < 2; ++p) {
    __syncthreads();                       // all reads of feats / previous h done
    if ((wid >> 1) == p) {                 // waves whose hcols fall in this half write h
      const int hloc = 80 * (wid & 1);
      #pragma unroll
      for (int af = 0; af < 5; ++af) {
        #pragma unroll
        for (int ef = 0; ef < 4; ++ef) {
          ushort4 q;
          q.x = f2bf(acc[af][ef][0]);
          q.y = f2bf(acc[af][ef][1]);
          q.z = f2bf(acc[af][ef][2]);
          q.w = f2bf(acc[af][ef][3]);      // 4 contiguous hcols, fixed edge
          *(ushort4*)(hbuf + (16 * ef + l15) * 168 + hloc + 16 * af + 4 * g) = q;
        }
      }
    }
    __syncthreads();
    #pragma unroll
    for (int kk = 0; kk < 5; ++kk) {
      const int kb = p * 160 + kk * 32 + 8 * g;
      const bf8 a0 = *(const bf8*)(w2t + l15 * 320 + kb);          // W2^T, L1-resident
      const bf8 a1 = *(const bf8*)(w2t + (16 + l15) * 320 + kb);
      const bf8 h0 = *(const bf8*)(hbuf + (we + l15) * 168 + kk * 32 + 8 * g);
      acc2[0] = __builtin_amdgcn_mfma_f32_16x16x32_bf16(a0, h0, acc2[0], 0, 0, 0);
      acc2[1] = __builtin_amdgcn_mfma_f32_16x16x32_bf16(a1, h0, acc2[1], 0, 0, 0);
    }
  }

  // ---- epilogue: + b2, store out[edge][32] f32 as contiguous float4s ----
  #pragma unroll
  for (int am = 0; am < 2; ++am) {
    const f4 b2v = *(const f4*)(b2 + 16 * am + 4 * g);
    const f4 v = acc2[am] + b2v;
    const long e = e0 + we + l15;
    *(f4*)(out + e * 32 + 16 * am + 4 * g) = v;
  }
}

extern "C" void kernel_launch(void* const* d_in, const int* in_sizes, int n_in,
                              void* d_out, int out_size, void* d_ws, size_t ws_size,
                              hipStream_t stream) {
  const float* nodes     = (const float*)d_in[0];
  const float* edges     = (const float*)d_in[1];
  const int*   senders   = (const int*)d_in[2];
  const int*   receivers = (const int*)d_in[3];
  const float* W1        = (const float*)d_in[4];
  const float* b1        = (const float*)d_in[5];
  const float* W2        = (const float*)d_in[6];
  const float* b2        = (const float*)d_in[7];
  float* out             = (float*)d_out;

  u16* w1t      = (u16*)d_ws;          // 51200 elems = 102400 B
  u16* w2t      = w1t + 51200;         // 10240 elems = 20480 B
  u16* nodes_bf = w2t + 10240;         // 3.2M elems = 6.4 MB (optional)
  const int use_bf = (ws_size >= (size_t)(122880 + 6400000)) ? 1 : 0;

  const int prep_blocks = use_bf ? (240 + 3125) : 240;
  prep_kernel<<<prep_blocks, 256, 0, stream>>>(nodes, W1, W2, w1t, w2t, nodes_bf);
  edge_mlp<<<NBLOCKS, 256, 0, stream>>>(edges, senders, receivers, nodes, nodes_bf,
                                        w1t, b1, w2t, b2, out, use_bf);
}